// Round 3
// baseline (363.956 us; speedup 1.0000x reference)
//
#include <hip/hip_runtime.h>

// B=8, N=100000, C=80: 800000 rows of 85 f32.
// Out: det [rows*7] f32, then valid [rows] f32 (0/1).

#define ROW      85
#define NCLS     80
#define TILE     32      // rows per block (10880 B LDS -> 15 blocks/CU = 30 waves/CU)
#define THREADS  128     // 2 waves; 4 lanes cooperate per row (20 classes each)
#define CONF_THRES 0.05f

__global__ __launch_bounds__(THREADS) void detect_kernel(
    const float* __restrict__ pred,   // [rows][85]
    float* __restrict__ det,          // [rows][7]
    float* __restrict__ valid,        // [rows]
    int rows)
{
    __shared__ float lds[TILE * ROW];   // 2720 f32 = 10880 B

    const int tile0 = blockIdx.x * TILE;
    const int nrows = min(TILE, rows - tile0);
    if (nrows <= 0) return;

    if (nrows == TILE) {
        // 680 float4 = 10880 B per tile; base is 16B-aligned (10880 % 16 == 0).
        const float4* __restrict__ src = (const float4*)(pred + (size_t)tile0 * ROW);
        float4* dst = (float4*)lds;
        #pragma unroll
        for (int it = 0; it < 5; ++it)
            dst[threadIdx.x + THREADS * it] = src[threadIdx.x + THREADS * it];
        if (threadIdx.x < 680 - 5 * THREADS)
            dst[5 * THREADS + threadIdx.x] = src[5 * THREADS + threadIdx.x];
    } else {
        const float* __restrict__ src = pred + (size_t)tile0 * ROW;
        for (int i = threadIdx.x; i < nrows * ROW; i += THREADS)
            lds[i] = src[i];
    }
    __syncthreads();

    // wave w handles rows [w*16, w*16+16); lane&15 picks the row,
    // quarter q = lane>>4 scans classes [q*20, q*20+20).
    const int wave      = threadIdx.x >> 6;
    const int lane      = threadIdx.x & 63;
    const int q         = lane >> 4;
    const int row_local = wave * 16 + (lane & 15);
    const float* row    = lds + row_local * ROW;

    const int kbase = q * 20;
    float best = row[5 + kbase];
    int   bidx = kbase;
    #pragma unroll
    for (int j = 1; j < 20; ++j) {
        const float s = row[5 + kbase + j];
        if (s > best) { best = s; bidx = kbase + j; }   // strict > = first-max in range
    }

    // Butterfly combine across the 4 quarters; argmax with min-index tie-break
    // is order-independent, so xor-16 then xor-32 yields the row argmax in all lanes.
    #pragma unroll
    for (int m = 16; m <= 32; m <<= 1) {
        const float ob = __shfl_xor(best, m);
        const int   oi = __shfl_xor(bidx, m);
        if (ob > best || (ob == best && oi < bidx)) { best = ob; bidx = oi; }
    }

    if (q == 0 && row_local < nrows) {
        const float x = row[0], y = row[1], w = row[2], h = row[3], conf = row[4];
        const float v = (conf >= CONF_THRES) ? 1.0f : 0.0f;
        const int   r = tile0 + row_local;
        float* o = det + (size_t)r * 7;
        o[0] = x * v;
        o[1] = y * v;
        o[2] = w * v;
        o[3] = h * v;
        o[4] = conf * v;
        o[5] = best * v;
        o[6] = (float)bidx * v;
        valid[r] = v;
    }
}

extern "C" void kernel_launch(void* const* d_in, const int* in_sizes, int n_in,
                              void* d_out, int out_size, void* d_ws, size_t ws_size,
                              hipStream_t stream)
{
    const float* pred = (const float*)d_in[0];
    const int rows = in_sizes[0] / ROW;          // 800000
    float* out = (float*)d_out;
    float* det = out;                            // rows*7
    float* valid = out + (size_t)rows * 7;       // rows

    const int blocks = (rows + TILE - 1) / TILE; // 25000
    detect_kernel<<<blocks, THREADS, 0, stream>>>(pred, det, valid, rows);
}